// Round 7
// baseline (134.067 us; speedup 1.0000x reference)
//
#include <hip/hip_runtime.h>
#include <hip/hip_bf16.h>

#define NB 32
#define NN 2048
#define DD 64
#define SQC 0.4246613965f  // sqrt(0.125 * LOG2E); applied to both Q and K

typedef __attribute__((ext_vector_type(8))) short short8;
typedef __attribute__((ext_vector_type(16))) float f32x16;
typedef __attribute__((ext_vector_type(4))) unsigned uint4v;
typedef __attribute__((ext_vector_type(4))) int int4v;

#define MFMA32B(A, B, C) \
  __builtin_amdgcn_mfma_f32_32x32x16_bf16((A), (B), (C), 0, 0, 0)

#define GLOAD_LDS16(gp, lp)                                                   \
  __builtin_amdgcn_global_load_lds(                                          \
      (const __attribute__((address_space(1))) void*)(gp),                   \
      (__attribute__((address_space(3))) void*)(lp), 16, 0, 0)

__device__ __forceinline__ short f2bf(float x) {
  __bf16 h = (__bf16)x;
  return __builtin_bit_cast(short, h);
}

__device__ __forceinline__ float fast_exp2(float x) {
#if __has_builtin(__builtin_amdgcn_exp2f)
  return __builtin_amdgcn_exp2f(x);
#else
  return exp2f(x);
#endif
}

// ---- 32x32x16 layouts (A: m=l&31, k=(l>>5)*8+j; B: n=l&31, k=(l>>5)*8+j;
// C: col=l&31, row=(reg&3)+8*(reg>>2)+4*(l>>5)).
// Key permutation: A-row m of a K-fragment holds actual key KEY_OF_ROW(m):
#define KEY_OF_ROW(m) \
  ((((m) >> 3) & 1) * 16 + (((m) >> 2) & 1) * 8 + ((m) >> 4) * 4 + ((m) & 3))
// QK output reg r (lane-half h) maps to key koff(r,h) =
// 16*((r>>2)&1) + 8h + 4*(r>>3) + (r&3); pc0 = regs {0..3,8..11} = keys
// 8h+0..7, pc1 = regs {4..7,12..15} = keys 16+8h+0..7. V natural key order.

// ---------- fused prep (unchanged from flash14): fragment-major bf16 image
// + batch-independent expanded byte-masks mexp (4 MB).
__global__ __launch_bounds__(256) void prep_fused(
    const float* __restrict__ x, const int* __restrict__ adj,
    short* __restrict__ img, uint4v* __restrict__ mexp) {
  const int tid = threadIdx.x;
  const int c = blockIdx.x;   // 64-key window -> chunks 2c, 2c+1
  const int b = blockIdx.y;

  // K units (scaled by SQC, permuted rows)
#pragma unroll
  for (int i = 0; i < 2; ++i) {
    const int kc = tid + i * 256;
    const int u8 = kc >> 6, l = kc & 63;
    const int chl = u8 >> 2, dc = u8 & 3;
    const int m = l & 31, hA = l >> 5;
    const int grow = c * 64 + chl * 32 + KEY_OF_ROW(m);
    const float* src = x + ((size_t)(b * NN + grow)) * DD + dc * 16 + 8 * hA;
    float4 f0 = ((const float4*)src)[0];
    float4 f1 = ((const float4*)src)[1];
    short8 v;
    v[0] = f2bf(f0.x * SQC); v[1] = f2bf(f0.y * SQC);
    v[2] = f2bf(f0.z * SQC); v[3] = f2bf(f0.w * SQC);
    v[4] = f2bf(f1.x * SQC); v[5] = f2bf(f1.y * SQC);
    v[6] = f2bf(f1.z * SQC); v[7] = f2bf(f1.w * SQC);
    *(short8*)&img[((size_t)(b * 64 + 2 * c + chl) * 8 + dc) * 512 + l * 8] = v;
  }
  // V units (transposed gather, natural key order)
#pragma unroll
  for (int i = 0; i < 2; ++i) {
    const int vc = tid + i * 256;
    const int u8 = vc >> 6, l = vc & 63;
    const int chl = u8 >> 2, sub = u8 & 3;
    const int dh = sub >> 1, kh = sub & 1;
    const int d = dh * 32 + (l & 31);
    const int key0 = c * 64 + chl * 32 + kh * 16 + 8 * (l >> 5);
    short8 o;
#pragma unroll
    for (int j = 0; j < 8; ++j)
      o[j] = f2bf(x[((size_t)(b * NN + key0 + j)) * DD + d]);
    *(short8*)&img[((size_t)(b * 64 + 2 * c + chl) * 8 + 4 + sub) * 512 +
                   l * 8] = o;
  }

  // expanded masks: block (c,b) -> tile (qg = b>>1, cm = 2c + (b&1))
  if (tid < 128) {
    const int qg = b >> 1;
    const int cm = blockIdx.x * 2 + (b & 1);
    const int ql = tid;
    const int* ap = adj + (size_t)(qg * 128 + ql) * NN + cm * 32;
    int4v av[8];
#pragma unroll
    for (int j = 0; j < 8; ++j) av[j] = *(const int4v*)(ap + j * 4);
#pragma unroll
    for (int h = 0; h < 2; ++h) {
      uint4v mv;
#pragma unroll
      for (int wd = 0; wd < 4; ++wd) {
        unsigned word = 0;
#pragma unroll
        for (int t = 0; t < 4; ++t) {
          const int K = 16 * (wd & 1) + 8 * h + 4 * (wd >> 1) + t;
          word |= (av[K >> 2][K & 3] > 0 ? 0xFFu : 0u) << (8 * t);
        }
        mv[wd] = word;
      }
      mexp[((size_t)(qg * 64 + cm) * 2 + h) * 128 + ql] = mv;
    }
  }
}

// One phase m: [vmcnt(1)][barrier][stage pair m+1 -> other half, prefetch
// its mask][setprio(1) compute chunk 2m+p from half RH, buffer p][setprio(0)]
// Per-phase VMEM/lane = 4 gload_lds + 1 mask dwordx4, kv-first, so vmcnt(1)
// at next phase start guarantees the staged KV landed (mask dep is tracked
// by the compiler via its register).
#define PHASE_BODY(RH, MUSE, MLOAD, VM, DO_STAGE, CS0)                       \
  {                                                                          \
    asm volatile("s_waitcnt vmcnt(" VM ")" ::: "memory");                    \
    __builtin_amdgcn_s_barrier();                                            \
    const uint4v mcur = MUSE;                                                \
    if (DO_STAGE) {                                                          \
      const short* gs =                                                      \
          img_b + (size_t)((CS0) + (w >> 1)) * 4096 + l * 8;                 \
      short* ds = &sI[(((RH) ^ 1) * 2 + (w >> 1))][0];                       \
      GLOAD_LDS16(gs + ((w & 1) * 4 + 0) * 512, ds + ((w & 1) * 4 + 0) * 512);\
      GLOAD_LDS16(gs + ((w & 1) * 4 + 1) * 512, ds + ((w & 1) * 4 + 1) * 512);\
      GLOAD_LDS16(gs + ((w & 1) * 4 + 2) * 512, ds + ((w & 1) * 4 + 2) * 512);\
      GLOAD_LDS16(gs + ((w & 1) * 4 + 3) * 512, ds + ((w & 1) * 4 + 3) * 512);\
      asm volatile("" ::: "memory");                                         \
      MLOAD = *(const uint4v*)(mpt + (size_t)((CS0) + p) * 4096);            \
      asm volatile("" ::: "memory");                                         \
    }                                                                        \
    __builtin_amdgcn_s_setprio(1);                                           \
    const short* ring = sI[(RH)*2 + p];                                      \
    f32x16 s = MFMA32B(*(const short8*)&ring[0 * 512 + l * 8], qf[0], fz);   \
    s = MFMA32B(*(const short8*)&ring[1 * 512 + l * 8], qf[1], s);           \
    s = MFMA32B(*(const short8*)&ring[2 * 512 + l * 8], qf[2], s);           \
    s = MFMA32B(*(const short8*)&ring[3 * 512 + l * 8], qf[3], s);           \
    float e[16];                                                             \
    _Pragma("unroll") for (int r = 0; r < 16; ++r) e[r] = fast_exp2(s[r]);   \
    short8 pc0, pc1;                                                         \
    pc0[0] = f2bf(e[0]);  pc0[1] = f2bf(e[1]);                               \
    pc0[2] = f2bf(e[2]);  pc0[3] = f2bf(e[3]);                               \
    pc0[4] = f2bf(e[8]);  pc0[5] = f2bf(e[9]);                               \
    pc0[6] = f2bf(e[10]); pc0[7] = f2bf(e[11]);                              \
    pc1[0] = f2bf(e[4]);  pc1[1] = f2bf(e[5]);                               \
    pc1[2] = f2bf(e[6]);  pc1[3] = f2bf(e[7]);                               \
    pc1[4] = f2bf(e[12]); pc1[5] = f2bf(e[13]);                              \
    pc1[6] = f2bf(e[14]); pc1[7] = f2bf(e[15]);                              \
    uint4v u0 = __builtin_bit_cast(uint4v, pc0);                             \
    uint4v u1 = __builtin_bit_cast(uint4v, pc1);                             \
    u0[0] &= __builtin_amdgcn_perm(0u, mcur[0], 0x01010000u);                \
    u0[1] &= __builtin_amdgcn_perm(0u, mcur[0], 0x03030202u);                \
    u0[2] &= __builtin_amdgcn_perm(0u, mcur[2], 0x01010000u);                \
    u0[3] &= __builtin_amdgcn_perm(0u, mcur[2], 0x03030202u);                \
    u1[0] &= __builtin_amdgcn_perm(0u, mcur[1], 0x01010000u);                \
    u1[1] &= __builtin_amdgcn_perm(0u, mcur[1], 0x03030202u);                \
    u1[2] &= __builtin_amdgcn_perm(0u, mcur[3], 0x01010000u);                \
    u1[3] &= __builtin_amdgcn_perm(0u, mcur[3], 0x03030202u);                \
    pc0 = __builtin_bit_cast(short8, u0);                                    \
    pc1 = __builtin_bit_cast(short8, u1);                                    \
    acl = MFMA32B(ones8, pc0, acl);                                          \
    acl = MFMA32B(ones8, pc1, acl);                                          \
    acc[0] = MFMA32B(*(const short8*)&ring[4 * 512 + l * 8], pc0, acc[0]);   \
    acc[0] = MFMA32B(*(const short8*)&ring[5 * 512 + l * 8], pc1, acc[0]);   \
    acc[1] = MFMA32B(*(const short8*)&ring[6 * 512 + l * 8], pc0, acc[1]);   \
    acc[1] = MFMA32B(*(const short8*)&ring[7 * 512 + l * 8], pc1, acc[1]);   \
    __builtin_amdgcn_s_setprio(0);                                           \
  }

// ---------- main: chunk-parity split. Block = 64 q (2 tiles x 32), 4 waves;
// wave (t,p) computes tile t over chunks c ≡ p (mod 2), 32 phases. Partial
// (acc, rowsum) pairs merge via LDS in the epilogue. Grid 1024 -> 4
// blocks/CU = 16 waves/CU (2x flash14). LDS: 4 x 8 KB chunk buffers
// (half per pair-parity, double-buffered). beta&7 = XCD, 4 batches/XCD.
__global__ __launch_bounds__(256, 4) void gat_flash15(
    const float* __restrict__ x, const short* __restrict__ img,
    const char* __restrict__ mexp, float* __restrict__ out) {
  __shared__ short sI[4][4096];

  const int beta = blockIdx.x;
  const int xcd = beta & 7;
  const int idx = beta >> 3;       // 0..127
  const int qg = idx & 31;         // 64-row q-group
  const int b = xcd * 4 + (idx >> 5);

  const int tid = threadIdx.x;
  const int w = tid >> 6;
  const int l = tid & 63;
  const int t = w >> 1;            // q-tile within block
  const int p = w & 1;             // chunk parity
  const int h = l >> 5;
  const int ql64 = t * 32 + (l & 31);
  const int q = qg * 64 + ql64;

  const short* img_b = img + (size_t)b * 64 * 8 * 512;
  const char* mpt = mexp + ((size_t)((qg >> 1) * 128 + h) * 128 +
                            (qg & 1) * 64 + ql64) * 16;  // chunk stride 4096

  // Q B-frags from x (scaled by SQC): qf[dc], elem j = Q[q, dc*16+8h+j]*SQC
  short8 qf[4];
  {
    const float* qs = x + ((size_t)(b * NN + q)) * DD + 8 * h;
#pragma unroll
    for (int dc = 0; dc < 4; ++dc) {
      float4 f0 = ((const float4*)(qs + dc * 16))[0];
      float4 f1 = ((const float4*)(qs + dc * 16))[1];
      short8 v;
      v[0] = f2bf(f0.x * SQC); v[1] = f2bf(f0.y * SQC);
      v[2] = f2bf(f0.z * SQC); v[3] = f2bf(f0.w * SQC);
      v[4] = f2bf(f1.x * SQC); v[5] = f2bf(f1.y * SQC);
      v[6] = f2bf(f1.z * SQC); v[7] = f2bf(f1.w * SQC);
      qf[dc] = v;
    }
  }

  f32x16 acc[2], acl, fz;
#pragma unroll
  for (int z = 0; z < 16; ++z) {
    acc[0][z] = 0.f; acc[1][z] = 0.f; acl[z] = 0.f; fz[z] = 0.f;
  }

  short8 ones8;
#pragma unroll
  for (int j = 0; j < 8; ++j) ones8[j] = 0x3F80;

  uint4v mA, mB;

  // prologue: stage pair 0 (chunks 0,1) into half 0; mask for chunk p
  {
    const short* gs = img_b + (size_t)(w >> 1) * 4096 + l * 8;
    short* ds = &sI[w >> 1][0];
#pragma unroll
    for (int i = 0; i < 4; ++i) {
      const int uu = (w & 1) * 4 + i;
      GLOAD_LDS16(gs + uu * 512, ds + uu * 512);
    }
    asm volatile("" ::: "memory");
    mA = *(const uint4v*)(mpt + (size_t)p * 4096);
    asm volatile("" ::: "memory");
  }

  // phases m=0..31; phase m computes chunk 2m+p, stages pair m+1 (m<31)
  for (int M = 0; M < 15; ++M) {
    PHASE_BODY(0, mA, mB, "1", true, 4 * M + 2);
    PHASE_BODY(1, mB, mA, "1", true, 4 * M + 4);
  }
  PHASE_BODY(0, mA, mB, "1", true, 62);  // m=30
  PHASE_BODY(1, mB, mA, "0", false, 0);  // m=31

  // ---- epilogue: merge parity partials via LDS, then write ----
  __syncthreads();
  float* red = (float*)sI;
  if (p == 1) {
    float* dst = red + (size_t)(t * 64 + l) * 33;
#pragma unroll
    for (int dh = 0; dh < 2; ++dh)
#pragma unroll
      for (int r = 0; r < 16; ++r) dst[dh * 16 + r] = acc[dh][r];
    dst[32] = acl[0];
  }
  __syncthreads();
  if (p == 0) {
    const float* src = red + (size_t)(t * 64 + l) * 33;
    const float inv = 1.0f / (acl[0] + src[32]);
    float* op = out + ((size_t)(b * NN + q)) * DD;
#pragma unroll
    for (int dh = 0; dh < 2; ++dh)
#pragma unroll
      for (int qd = 0; qd < 4; ++qd) {
        float4 o;
        o.x = (acc[dh][qd * 4 + 0] + src[dh * 16 + qd * 4 + 0]) * inv;
        o.y = (acc[dh][qd * 4 + 1] + src[dh * 16 + qd * 4 + 1]) * inv;
        o.z = (acc[dh][qd * 4 + 2] + src[dh * 16 + qd * 4 + 2]) * inv;
        o.w = (acc[dh][qd * 4 + 3] + src[dh * 16 + qd * 4 + 3]) * inv;
        *(float4*)(op + dh * 32 + 8 * qd + 4 * h) = o;
      }
  }
}

extern "C" void kernel_launch(void* const* d_in, const int* in_sizes, int n_in,
                              void* d_out, int out_size, void* d_ws,
                              size_t ws_size, hipStream_t stream) {
  const float* x = (const float*)d_in[0];
  const int* adj = (const int*)d_in[1];
  float* out = (float*)d_out;

  short* img = (short*)d_ws;                                   // 16 MB
  uint4v* mexp = (uint4v*)(img + (size_t)NB * 64 * 8 * 512);   // 4 MB

  prep_fused<<<dim3(32, NB), 256, 0, stream>>>(x, adj, img, mexp);
  gat_flash15<<<1024, 256, 0, stream>>>(x, img, (const char*)mexp, out);
}

// Round 8
// 126.325 us; speedup vs baseline: 1.0613x; 1.0613x over previous
//
#include <hip/hip_runtime.h>
#include <hip/hip_bf16.h>

#define NB 32
#define NN 2048
#define DD 64
#define SQC 0.4246613965f  // sqrt(0.125 * LOG2E); applied to both Q and K

typedef __attribute__((ext_vector_type(8))) short short8;
typedef __attribute__((ext_vector_type(16))) float f32x16;
typedef __attribute__((ext_vector_type(4))) unsigned uint4v;
typedef __attribute__((ext_vector_type(4))) int int4v;

#define MFMA32B(A, B, C) \
  __builtin_amdgcn_mfma_f32_32x32x16_bf16((A), (B), (C), 0, 0, 0)

#define GLOAD_LDS16(gp, lp)                                                   \
  __builtin_amdgcn_global_load_lds(                                          \
      (const __attribute__((address_space(1))) void*)(gp),                   \
      (__attribute__((address_space(3))) void*)(lp), 16, 0, 0)

__device__ __forceinline__ short f2bf(float x) {
  __bf16 h = (__bf16)x;
  return __builtin_bit_cast(short, h);
}

__device__ __forceinline__ float fast_exp2(float x) {
#if __has_builtin(__builtin_amdgcn_exp2f)
  return __builtin_amdgcn_exp2f(x);
#else
  return exp2f(x);
#endif
}

// ---- 32x32x16 layouts (A: m=l&31, k=(l>>5)*8+j; B: n=l&31, k=(l>>5)*8+j;
// C: col=l&31, row=(reg&3)+8*(reg>>2)+4*(l>>5)).
// Key permutation: A-row m of a K-fragment holds actual key KEY_OF_ROW(m):
#define KEY_OF_ROW(m) \
  ((((m) >> 3) & 1) * 16 + (((m) >> 2) & 1) * 8 + ((m) >> 4) * 4 + ((m) & 3))
// QK output reg r (lane-half h) maps to key koff(r,h) =
// 16*((r>>2)&1) + 8h + 4*(r>>3) + (r&3); pc0 = regs {0..3,8..11} = keys
// 8h+0..7, pc1 = regs {4..7,12..15} = keys 16+8h+0..7. V natural key order.

// ---------- fused prep: fragment-major bf16 image + batch-independent
// expanded byte-masks, PAIR-INTERLEAVED: the 16-B mask words of chunks
// 2i and 2i+1 are adjacent (uint4v index
// ((qg*64 + 2i + h)*128 + ql)*2 + (chunk&1)) so the main kernel's 2-chunk
// phases load both with two adjacent 16-B loads.
__global__ __launch_bounds__(256) void prep_fused(
    const float* __restrict__ x, const int* __restrict__ adj,
    short* __restrict__ img, uint4v* __restrict__ mexp) {
  const int tid = threadIdx.x;
  const int c = blockIdx.x;   // 64-key window -> chunks 2c, 2c+1
  const int b = blockIdx.y;

  // K units (scaled by SQC, permuted rows)
#pragma unroll
  for (int i = 0; i < 2; ++i) {
    const int kc = tid + i * 256;
    const int u8 = kc >> 6, l = kc & 63;
    const int chl = u8 >> 2, dc = u8 & 3;
    const int m = l & 31, hA = l >> 5;
    const int grow = c * 64 + chl * 32 + KEY_OF_ROW(m);
    const float* src = x + ((size_t)(b * NN + grow)) * DD + dc * 16 + 8 * hA;
    float4 f0 = ((const float4*)src)[0];
    float4 f1 = ((const float4*)src)[1];
    short8 v;
    v[0] = f2bf(f0.x * SQC); v[1] = f2bf(f0.y * SQC);
    v[2] = f2bf(f0.z * SQC); v[3] = f2bf(f0.w * SQC);
    v[4] = f2bf(f1.x * SQC); v[5] = f2bf(f1.y * SQC);
    v[6] = f2bf(f1.z * SQC); v[7] = f2bf(f1.w * SQC);
    *(short8*)&img[((size_t)(b * 64 + 2 * c + chl) * 8 + dc) * 512 + l * 8] = v;
  }
  // V units (transposed gather, natural key order)
#pragma unroll
  for (int i = 0; i < 2; ++i) {
    const int vc = tid + i * 256;
    const int u8 = vc >> 6, l = vc & 63;
    const int chl = u8 >> 2, sub = u8 & 3;
    const int dh = sub >> 1, kh = sub & 1;
    const int d = dh * 32 + (l & 31);
    const int key0 = c * 64 + chl * 32 + kh * 16 + 8 * (l >> 5);
    short8 o;
#pragma unroll
    for (int j = 0; j < 8; ++j)
      o[j] = f2bf(x[((size_t)(b * NN + key0 + j)) * DD + d]);
    *(short8*)&img[((size_t)(b * 64 + 2 * c + chl) * 8 + 4 + sub) * 512 +
                   l * 8] = o;
  }

  // expanded masks: block (c,b) -> tile (qg = b>>1, cm = 2c + (b&1))
  if (tid < 128) {
    const int qg = b >> 1;
    const int cm = blockIdx.x * 2 + (b & 1);
    const int ql = tid;
    const int* ap = adj + (size_t)(qg * 128 + ql) * NN + cm * 32;
    int4v av[8];
#pragma unroll
    for (int j = 0; j < 8; ++j) av[j] = *(const int4v*)(ap + j * 4);
#pragma unroll
    for (int h = 0; h < 2; ++h) {
      uint4v mv;
#pragma unroll
      for (int wd = 0; wd < 4; ++wd) {
        unsigned word = 0;
#pragma unroll
        for (int t = 0; t < 4; ++t) {
          const int K = 16 * (wd & 1) + 8 * h + 4 * (wd >> 1) + t;
          word |= (av[K >> 2][K & 3] > 0 ? 0xFFu : 0u) << (8 * t);
        }
        mv[wd] = word;
      }
      mexp[(((size_t)qg * 64 + (cm >> 1) * 2 + h) * 128 + ql) * 2 +
           (cm & 1)] = mv;
    }
  }
}

// stage one 16-KB pair (16 units of 1 KB) split across 4 waves
#define STAGE_PAIR(PAIR, SLOT)                                               \
  {                                                                          \
    const short* gs = img_b + (size_t)(PAIR) * 8192 + l * 8;                 \
    short* ds = &sI[SLOT][0];                                                \
    GLOAD_LDS16(gs + (w + 0) * 512, ds + (w + 0) * 512);                     \
    GLOAD_LDS16(gs + (w + 4) * 512, ds + (w + 4) * 512);                     \
    GLOAD_LDS16(gs + (w + 8) * 512, ds + (w + 8) * 512);                     \
    GLOAD_LDS16(gs + (w + 12) * 512, ds + (w + 12) * 512);                   \
  }

// masked bf16 pack of one chunk's 16 exp values -> pc0/pc1 B-frags
#define PACK_MASK(EV, MC, PC0, PC1)                                          \
  {                                                                          \
    short8 t0, t1;                                                           \
    t0[0] = f2bf(EV[0]);  t0[1] = f2bf(EV[1]);                               \
    t0[2] = f2bf(EV[2]);  t0[3] = f2bf(EV[3]);                               \
    t0[4] = f2bf(EV[8]);  t0[5] = f2bf(EV[9]);                               \
    t0[6] = f2bf(EV[10]); t0[7] = f2bf(EV[11]);                              \
    t1[0] = f2bf(EV[4]);  t1[1] = f2bf(EV[5]);                               \
    t1[2] = f2bf(EV[6]);  t1[3] = f2bf(EV[7]);                               \
    t1[4] = f2bf(EV[12]); t1[5] = f2bf(EV[13]);                              \
    t1[6] = f2bf(EV[14]); t1[7] = f2bf(EV[15]);                              \
    uint4v u0 = __builtin_bit_cast(uint4v, t0);                              \
    uint4v u1 = __builtin_bit_cast(uint4v, t1);                              \
    u0[0] &= __builtin_amdgcn_perm(0u, MC[0], 0x01010000u);                  \
    u0[1] &= __builtin_amdgcn_perm(0u, MC[0], 0x03030202u);                  \
    u0[2] &= __builtin_amdgcn_perm(0u, MC[2], 0x01010000u);                  \
    u0[3] &= __builtin_amdgcn_perm(0u, MC[2], 0x03030202u);                  \
    u1[0] &= __builtin_amdgcn_perm(0u, MC[1], 0x01010000u);                  \
    u1[1] &= __builtin_amdgcn_perm(0u, MC[1], 0x03030202u);                  \
    u1[2] &= __builtin_amdgcn_perm(0u, MC[3], 0x01010000u);                  \
    u1[3] &= __builtin_amdgcn_perm(0u, MC[3], 0x03030202u);                  \
    PC0 = __builtin_bit_cast(short8, u0);                                    \
    PC1 = __builtin_bit_cast(short8, u1);                                    \
  }

// One phase p (pair i = p): [vmcnt(VM)][barrier][load masks pair PAIRM]
// [stage KV pair PAIRS -> slot SLOTS][setprio(1) compute chunks 2i,2i+1 as
// two independent register streams][setprio(0)].  VMEM order per phase:
// 2 mask loads then 4 gload_lds, so vmcnt(4) at the next wait covers both
// this pair's KV (staged 2 phases ago) and its masks (loaded 1 phase ago).
#define PHASE_BODY(SLOT, MUE, MUO, MLE, MLO, VM, DO_MASK, PAIRM, DO_STAGE,   \
                   PAIRS, SLOTS)                                             \
  {                                                                          \
    asm volatile("s_waitcnt vmcnt(" VM ")" ::: "memory");                    \
    __builtin_amdgcn_s_barrier();                                            \
    const uint4v mE = MUE;                                                   \
    const uint4v mO = MUO;                                                   \
    if (DO_MASK) {                                                           \
      MLE = *(const uint4v*)(mpt + (size_t)(PAIRM) * 8192);                  \
      MLO = *(const uint4v*)(mpt + (size_t)(PAIRM) * 8192 + 16);             \
    }                                                                        \
    asm volatile("" ::: "memory");                                           \
    if (DO_STAGE) STAGE_PAIR(PAIRS, SLOTS);                                  \
    asm volatile("" ::: "memory");                                           \
    __builtin_amdgcn_s_setprio(1);                                           \
    const short* rE = &sI[SLOT][0];                                          \
    const short* rO = &sI[SLOT][4096];                                       \
    f32x16 sE = MFMA32B(*(const short8*)&rE[0 * 512 + l * 8], qf[0], fz);    \
    f32x16 sO = MFMA32B(*(const short8*)&rO[0 * 512 + l * 8], qf[0], fz);    \
    sE = MFMA32B(*(const short8*)&rE[1 * 512 + l * 8], qf[1], sE);           \
    sO = MFMA32B(*(const short8*)&rO[1 * 512 + l * 8], qf[1], sO);           \
    sE = MFMA32B(*(const short8*)&rE[2 * 512 + l * 8], qf[2], sE);           \
    sO = MFMA32B(*(const short8*)&rO[2 * 512 + l * 8], qf[2], sO);           \
    sE = MFMA32B(*(const short8*)&rE[3 * 512 + l * 8], qf[3], sE);           \
    sO = MFMA32B(*(const short8*)&rO[3 * 512 + l * 8], qf[3], sO);           \
    float eE[16], eO[16];                                                    \
    _Pragma("unroll") for (int r = 0; r < 16; ++r) {                         \
      eE[r] = fast_exp2(sE[r]);                                              \
      eO[r] = fast_exp2(sO[r]);                                              \
    }                                                                        \
    short8 pc0E, pc1E, pc0O, pc1O;                                           \
    PACK_MASK(eE, mE, pc0E, pc1E);                                           \
    PACK_MASK(eO, mO, pc0O, pc1O);                                           \
    acl = MFMA32B(ones8, pc0E, acl);                                         \
    acl = MFMA32B(ones8, pc1E, acl);                                         \
    acl = MFMA32B(ones8, pc0O, acl);                                         \
    acl = MFMA32B(ones8, pc1O, acl);                                         \
    accE[0] = MFMA32B(*(const short8*)&rE[4 * 512 + l * 8], pc0E, accE[0]);  \
    accO[0] = MFMA32B(*(const short8*)&rO[4 * 512 + l * 8], pc0O, accO[0]);  \
    accE[0] = MFMA32B(*(const short8*)&rE[5 * 512 + l * 8], pc1E, accE[0]);  \
    accO[0] = MFMA32B(*(const short8*)&rO[5 * 512 + l * 8], pc1O, accO[0]);  \
    accE[1] = MFMA32B(*(const short8*)&rE[6 * 512 + l * 8], pc0E, accE[1]);  \
    accO[1] = MFMA32B(*(const short8*)&rO[6 * 512 + l * 8], pc0O, accO[1]);  \
    accE[1] = MFMA32B(*(const short8*)&rE[7 * 512 + l * 8], pc1E, accE[1]);  \
    accO[1] = MFMA32B(*(const short8*)&rO[7 * 512 + l * 8], pc1O, accO[1]);  \
    __builtin_amdgcn_s_setprio(0);                                           \
  }

// ---------- main: flash14 resource footprint (512 blocks x 4 waves, 2
// blocks/CU) but 2 independent chunk streams per phase (double intra-wave
// ILP, half the barriers). Ring-3 of 16-KB pairs (48 KB LDS); counted
// vmcnt(4); separate E/O PV accumulators merged in registers.
__global__ __launch_bounds__(256, 2) void gat_flash16(
    const float* __restrict__ x, const short* __restrict__ img,
    const char* __restrict__ mexp, float* __restrict__ out) {
  __shared__ short sI[3][8192];

  const int beta = blockIdx.x;
  const int xcd = beta & 7;
  const int idx = beta >> 3;       // 0..63
  const int qg = idx & 15;         // 128-row q-group
  const int b = xcd * 4 + (idx >> 4);

  const int tid = threadIdx.x;
  const int w = tid >> 6;
  const int l = tid & 63;
  const int h = l >> 5;
  const int ql = w * 32 + (l & 31);
  const int q = qg * 128 + ql;

  const short* img_b = img + (size_t)b * 64 * 8 * 512;
  const char* mpt =
      mexp + ((size_t)((qg * 64 + h) * 128) + ql) * 32;  // pair stride 8192 B

  // Q B-frags from x (scaled by SQC): qf[dc], elem j = Q[q, dc*16+8h+j]*SQC
  short8 qf[4];
  {
    const float* qs = x + ((size_t)(b * NN + q)) * DD + 8 * h;
#pragma unroll
    for (int dc = 0; dc < 4; ++dc) {
      float4 f0 = ((const float4*)(qs + dc * 16))[0];
      float4 f1 = ((const float4*)(qs + dc * 16))[1];
      short8 v;
      v[0] = f2bf(f0.x * SQC); v[1] = f2bf(f0.y * SQC);
      v[2] = f2bf(f0.z * SQC); v[3] = f2bf(f0.w * SQC);
      v[4] = f2bf(f1.x * SQC); v[5] = f2bf(f1.y * SQC);
      v[6] = f2bf(f1.z * SQC); v[7] = f2bf(f1.w * SQC);
      qf[dc] = v;
    }
  }

  f32x16 accE[2], accO[2], acl, fz;
#pragma unroll
  for (int z = 0; z < 16; ++z) {
    accE[0][z] = 0.f; accE[1][z] = 0.f;
    accO[0][z] = 0.f; accO[1][z] = 0.f;
    acl[z] = 0.f; fz[z] = 0.f;
  }

  short8 ones8;
#pragma unroll
  for (int j = 0; j < 8; ++j) ones8[j] = 0x3F80;

  uint4v mAE, mAO, mBE, mBO;

  // prologue: masks pair 0, then KV pairs 0,1 -> slots 0,1
  mAE = *(const uint4v*)(mpt);
  mAO = *(const uint4v*)(mpt + 16);
  asm volatile("" ::: "memory");
  STAGE_PAIR(0, 0);
  STAGE_PAIR(1, 1);
  asm volatile("" ::: "memory");

  // 32 phases; phase p computes pair p, loads masks p+1, stages KV p+2
  for (int M = 0; M < 5; ++M) {
    const int i0 = 6 * M;
    PHASE_BODY(0, mAE, mAO, mBE, mBO, "4", true, i0 + 1, true, i0 + 2, 2);
    PHASE_BODY(1, mBE, mBO, mAE, mAO, "4", true, i0 + 2, true, i0 + 3, 0);
    PHASE_BODY(2, mAE, mAO, mBE, mBO, "4", true, i0 + 3, true, i0 + 4, 1);
    PHASE_BODY(0, mBE, mBO, mAE, mAO, "4", true, i0 + 4, true, i0 + 5, 2);
    PHASE_BODY(1, mAE, mAO, mBE, mBO, "4", true, i0 + 5, true, i0 + 6, 0);
    PHASE_BODY(2, mBE, mBO, mAE, mAO, "4", true, i0 + 6, true, i0 + 7, 1);
  }
  PHASE_BODY(0, mAE, mAO, mBE, mBO, "4", true, 31, false, 0, 2);  // p=30
  PHASE_BODY(1, mBE, mBO, mAE, mAO, "0", false, 0, false, 0, 0);  // p=31

  // ---- epilogue: register merge of E/O partials, then write ----
  const float inv = 1.0f / acl[0];
  float* op = out + ((size_t)(b * NN + q)) * DD;
#pragma unroll
  for (int dh = 0; dh < 2; ++dh)
#pragma unroll
    for (int qd = 0; qd < 4; ++qd) {
      float4 o;
      o.x = (accE[dh][qd * 4 + 0] + accO[dh][qd * 4 + 0]) * inv;
      o.y = (accE[dh][qd * 4 + 1] + accO[dh][qd * 4 + 1]) * inv;
      o.z = (accE[dh][qd * 4 + 2] + accO[dh][qd * 4 + 2]) * inv;
      o.w = (accE[dh][qd * 4 + 3] + accO[dh][qd * 4 + 3]) * inv;
      *(float4*)(op + dh * 32 + 8 * qd + 4 * h) = o;
    }
}

extern "C" void kernel_launch(void* const* d_in, const int* in_sizes, int n_in,
                              void* d_out, int out_size, void* d_ws,
                              size_t ws_size, hipStream_t stream) {
  const float* x = (const float*)d_in[0];
  const int* adj = (const int*)d_in[1];
  float* out = (float*)d_out;

  short* img = (short*)d_ws;                                   // 16 MB
  uint4v* mexp = (uint4v*)(img + (size_t)NB * 64 * 8 * 512);   // 4 MB

  prep_fused<<<dim3(32, NB), 256, 0, stream>>>(x, adj, img, mexp);
  gat_flash16<<<512, 256, 0, stream>>>(x, img, (const char*)mexp, out);
}